// Round 7
// baseline (351.022 us; speedup 1.0000x reference)
//
#include <hip/hip_runtime.h>
#include <hip/hip_bf16.h>
#include <math.h>

#define SCALE 0.08838834764831845f  // 1/sqrt(128)

using short8  = __attribute__((ext_vector_type(8))) short;
using short4v = __attribute__((ext_vector_type(4))) short;
using us4     = __attribute__((ext_vector_type(4))) unsigned short;
using f32x4   = __attribute__((ext_vector_type(4))) float;
typedef unsigned long long u64;
typedef unsigned short ushort_t;

static __device__ __forceinline__ ushort_t bf16_of(float f) {
    __hip_bfloat16 h = __float2bfloat16(f);
    return *reinterpret_cast<ushort_t*>(&h);
}
static __device__ __forceinline__ float f_of_bf16(unsigned int u) {
    union { unsigned int i; float f; } v; v.i = u << 16; return v.f;
}

// ---------------- fused prep kernel ----------------
// grid 3120 x 256:
//   [0,1024)    : x -> bf16
//   [1024,1072) : W -> bf16 transposed [3072][128]
//   [1072,3120) : mask bit-pack (8192 rows x 16 u64)
__global__ __launch_bounds__(256)
void prep_all(const float* __restrict__ x, ushort_t* __restrict__ xb,
              const float* __restrict__ wq, const float* __restrict__ wk,
              const float* __restrict__ wv, ushort_t* __restrict__ Wt,
              const int* __restrict__ mask, u64* __restrict__ mp) {
    __shared__ float tile[64][129];
    const int bx = blockIdx.x;
    const int tid = threadIdx.x;
    if (bx < 1024) {
        const int i = bx * 256 + tid;
        float4 v = reinterpret_cast<const float4*>(x)[i];
        short4v o;
        o.x = (short)bf16_of(v.x); o.y = (short)bf16_of(v.y);
        o.z = (short)bf16_of(v.z); o.w = (short)bf16_of(v.w);
        reinterpret_cast<short4v*>(xb)[i] = o;
    } else if (bx < 1072) {
        const int wb = bx - 1024;
        const int mat = wb >> 4;
        const int n0 = (wb & 15) * 64;
        const float* W = (mat == 0) ? wq : (mat == 1) ? wk : wv;
        for (int idx = tid; idx < 8192; idx += 256) {
            const int k = idx >> 6, c = idx & 63;
            tile[c][k] = W[(size_t)k * 1024 + n0 + c];
        }
        __syncthreads();
        for (int idx = tid; idx < 8192; idx += 256) {
            const int c = idx >> 7, k = idx & 127;
            Wt[(size_t)(mat * 1024 + n0 + c) * 128 + k] = bf16_of(tile[c][k]);
        }
    } else {
        const int mb = bx - 1072;
        const int row = mb * 4 + (tid >> 6);
        const int l = tid & 63;
        const int* m = mask + (size_t)row * 1024;
        #pragma unroll
        for (int c = 0; c < 16; ++c) {
            u64 bm = __ballot(m[c * 64 + l] != 0);
            if (l == 0) mp[(size_t)row * 16 + c] = bm;
        }
    }
}

// ---------------- MFMA projection GEMM ----------------
// grid (128, 48), block 256 (4 waves). mat = blockIdx.y>>4 (0 Q,1 K,2 V).
// All outputs row-major bf16 [hb][t][128]; Q pre-scaled.
__global__ __launch_bounds__(256)
void proj_gemm(const ushort_t* __restrict__ xb, const ushort_t* __restrict__ Wt,
               ushort_t* __restrict__ Q, ushort_t* __restrict__ K,
               ushort_t* __restrict__ V) {
    const int tid = threadIdx.x;
    const int w = tid >> 6, l = tid & 63;
    const int l15 = l & 15, lq = l >> 4;
    const int m0 = blockIdx.x * 64;
    const int nb = blockIdx.y;
    const int mat = nb >> 4;
    const int n0 = (nb & 15) * 64;
    const int b = m0 >> 10;

    short8 af[4][4];
    #pragma unroll
    for (int at = 0; at < 4; ++at) {
        const ushort_t* ar = xb + (size_t)(m0 + at * 16 + l15) * 128 + lq * 8;
        #pragma unroll
        for (int f = 0; f < 4; ++f)
            af[at][f] = *reinterpret_cast<const short8*>(ar + f * 32);
    }
    const int ng = n0 + w * 16 + l15;
    const ushort_t* br = Wt + (size_t)(mat * 1024 + ng) * 128 + lq * 8;
    short8 bf[4];
    #pragma unroll
    for (int f = 0; f < 4; ++f)
        bf[f] = *reinterpret_cast<const short8*>(br + f * 32);
    f32x4 acc[4];
    #pragma unroll
    for (int at = 0; at < 4; ++at) acc[at] = (f32x4){0.f, 0.f, 0.f, 0.f};
    #pragma unroll
    for (int at = 0; at < 4; ++at)
        #pragma unroll
        for (int f = 0; f < 4; ++f)
            acc[at] = __builtin_amdgcn_mfma_f32_16x16x32_bf16(af[at][f], bf[f], acc[at], 0, 0, 0);

    const int h = ng >> 7, e = ng & 127;
    ushort_t* O = (mat == 0) ? Q : (mat == 1) ? K : V;
    const float scl = (mat == 0) ? SCALE : 1.0f;
    const size_t obase = (size_t)(h * 8 + b) * 131072 + e;
    #pragma unroll
    for (int at = 0; at < 4; ++at)
        #pragma unroll
        for (int r = 0; r < 4; ++r) {
            const int t = (m0 & 1023) + at * 16 + lq * 4 + r;
            O[obase + (size_t)t * 128] = bf16_of(acc[at][r] * scl);
        }
}

// ---------------- gating (sel) kernel ----------------
__global__ __launch_bounds__(1024)
void sel_kernel(const float* __restrict__ x, const float* __restrict__ wsl,
                const float* __restrict__ bsl, float* __restrict__ sel) {
    __shared__ float part[8][128];
    __shared__ float xm[128];
    __shared__ float lg[8];
    const int b = blockIdx.x;
    const int tid = threadIdx.x;
    const int e = tid & 127, tc = tid >> 7;
    float s = 0.f;
    for (int t = 0; t < 128; ++t)
        s += x[((size_t)b * 1024 + tc * 128 + t) * 128 + e];
    part[tc][e] = s;
    __syncthreads();
    if (tid < 128) {
        float tot = 0.f;
        #pragma unroll
        for (int i = 0; i < 8; ++i) tot += part[i][tid];
        xm[tid] = tot * (1.0f / 1024.0f);
    }
    __syncthreads();
    if (tid < 8) {
        float d = 0.f;
        for (int e2 = 0; e2 < 128; ++e2) d += xm[e2] * wsl[tid * 128 + e2];
        lg[tid] = d + bsl[tid];
    }
    __syncthreads();
    if (tid == 0) {
        float mx = lg[0];
        for (int hh = 1; hh < 8; ++hh) mx = fmaxf(mx, lg[hh]);
        float se = 0.f; float ex[8];
        for (int hh = 0; hh < 8; ++hh) { ex[hh] = expf(lg[hh] - mx); se += ex[hh]; }
        for (int hh = 0; hh < 8; ++hh) sel[b * 8 + hh] = ex[hh] / se;
    }
}

// ---------------- MFMA attention: 2-pass staging, warm-start Michelot, sparse PV --------
// grid 4096 = 64 (h,b) * 64 q-tiles of 16 rows; block 512 (8 waves), 4 blocks/CU.
__global__ __launch_bounds__(512, 8)
void attn_kernel(const ushort_t* __restrict__ Qb, const ushort_t* __restrict__ Kb,
                 const ushort_t* __restrict__ Vb, const u64* __restrict__ mp,
                 const float* __restrict__ sel, float* __restrict__ out) {
    __shared__ float S[16 * 512];    // 32 KB half-S staging; support list aliases it later
    __shared__ int cnt[16];
    unsigned int* list = reinterpret_cast<unsigned int*>(S);

    const int tid = threadIdx.x;
    const int w = tid >> 6, l = tid & 63;
    const int l15 = l & 15, lq = l >> 4;
    const int qrow = tid >> 5;        // row owned for solve/compact/PV (2 rows per wave)
    const int lh = l & 31;
    const int hb = (int)blockIdx.x >> 6;
    const int qt = (int)blockIdx.x & 63;
    const int h = hb >> 3, b = hb & 7;
    const int t0 = qt * 16;
    const size_t base = (size_t)hb * 131072;
    const int rowbase = b * 1024 + t0;

    if (tid < 16) cnt[tid] = 0;

    // ---- Q A-frags ----
    short8 qa[4];
    {
        const ushort_t* qrp = Qb + base + (size_t)(t0 + l15) * 128 + lq * 8;
        #pragma unroll
        for (int f = 0; f < 4; ++f)
            qa[f] = *reinterpret_cast<const short8*>(qrp + f * 32);
    }

    float z[32];

    // ---- two half-K passes: QK^T (4 ktiles/wave) -> mask -> stage -> transpose-read ----
    #pragma unroll
    for (int pass = 0; pass < 2; ++pass) {
        f32x4 sc[4];
        #pragma unroll
        for (int i = 0; i < 4; ++i) {
            const int kt = pass * 32 + w * 4 + i;
            const ushort_t* krow = Kb + base + (size_t)(kt * 16 + l15) * 128 + lq * 8;
            f32x4 acc = {0.f, 0.f, 0.f, 0.f};
            #pragma unroll
            for (int f = 0; f < 4; ++f) {
                short8 kb = *reinterpret_cast<const short8*>(krow + f * 32);
                acc = __builtin_amdgcn_mfma_f32_16x16x32_bf16(qa[f], kb, acc, 0, 0, 0);
            }
            sc[i] = acc;
        }
        // mask word (pass*8 + w) covers this wave's 64 cols
        #pragma unroll
        for (int r = 0; r < 4; ++r) {
            const int q = lq * 4 + r;
            const u64 mw = mp[(size_t)(rowbase + q) * 16 + pass * 8 + w];
            #pragma unroll
            for (int i = 0; i < 4; ++i) {
                const int bit = i * 16 + l15;
                if ((mw >> bit) & 1ULL) sc[i][r] = -1e30f;
            }
        }
        // stage (chunk-swizzled)
        #pragma unroll
        for (int r = 0; r < 4; ++r) {
            const int q = lq * 4 + r;
            #pragma unroll
            for (int i = 0; i < 4; ++i) {
                const int c = (w * 4 + i) * 4 + (l15 >> 2);        // local chunk 0..127
                const int cp = c ^ ((c >> 3) & 7) ^ (q & 7);
                S[q * 512 + cp * 4 + (l15 & 3)] = sc[i][r];
            }
        }
        __syncthreads();
        // transpose read: lane owns cols 4*lh+128*j+m of its row (this half)
        #pragma unroll
        for (int j = 0; j < 4; ++j) {
            const int c = lh + 32 * j;
            const int cp = c ^ ((c >> 3) & 7) ^ (qrow & 7);
            float4 v = *reinterpret_cast<const float4*>(&S[qrow * 512 + cp * 4]);
            z[pass * 16 + 4 * j + 0] = v.x; z[pass * 16 + 4 * j + 1] = v.y;
            z[pass * 16 + 4 * j + 2] = v.z; z[pass * 16 + 4 * j + 3] = v.w;
        }
        __syncthreads();
    }

    // ---- row max (tree + 5 shfl within 32-lane half) ----
    float m16[16];
    #pragma unroll
    for (int j = 0; j < 16; ++j) m16[j] = fmaxf(z[j], z[j + 16]);
    #pragma unroll
    for (int j = 0; j < 8; ++j) m16[j] = fmaxf(m16[j], m16[j + 8]);
    #pragma unroll
    for (int j = 0; j < 4; ++j) m16[j] = fmaxf(m16[j], m16[j + 4]);
    float mx = fmaxf(fmaxf(m16[0], m16[1]), fmaxf(m16[2], m16[3]));
    #pragma unroll
    for (int mm = 1; mm <= 16; mm <<= 1) mx = fmaxf(mx, __shfl_xor(mx, mm));

    // ---- Michelot sparsemax, warm start from {z > mx-1} (superset of support) ----
    float tau;
    if (mx < -1e29f) {
        tau = 3e38f;                   // fully-masked row
    } else {
        tau = mx - 1.0f;
        unsigned prev = 0xFFFFFFFFu;
        for (int it = 0; it < 64; ++it) {
            float s2 = 0.f; unsigned c2 = 0u;
            #pragma unroll
            for (int k = 0; k < 32; ++k) {
                const float zz = z[k];
                s2 += (zz > tau) ? zz : 0.f;
                c2 += (zz > tau) ? 1u : 0u;
            }
            #pragma unroll
            for (int mm = 1; mm <= 16; mm <<= 1) {
                s2 += __shfl_xor(s2, mm);
                c2 += __shfl_xor(c2, mm);
            }
            if (c2 == prev) break;     // per-row uniform; shfl partners stay in-row
            tau = (s2 - 1.f) / (float)c2;
            prev = c2;
        }
    }

    // ---- compact support (k, p-bf16) into list ----
    #pragma unroll
    for (int jj = 0; jj < 32; ++jj) {
        const float p = z[jj] - tau;
        if (p > 0.f) {
            const int k = ((jj & 16) << 5) + 4 * lh + 128 * ((jj >> 2) & 3) + (jj & 3);
            const int pos = atomicAdd(&cnt[qrow], 1);
            if (pos < 512)
                list[qrow * 512 + pos] = (unsigned int)k | ((unsigned int)bf16_of(p) << 16);
        }
    }
    // same-wave RAW on cnt/list (rows owned by this wave) -> no barrier needed

    // ---- sparse PV: half-wave = row, lane = e-quad; out_row += p * V[k][:] ----
    const int eq = tid & 31;
    int n = cnt[qrow]; n = (n < 512) ? n : 512;
    const ushort_t* Vrow = Vb + base;
    const unsigned int* lrow = list + qrow * 512;
    float a0 = 0.f, a1 = 0.f, a2 = 0.f, a3 = 0.f;
    for (int j = 0; j < n; ++j) {
        const unsigned int ent = lrow[j];
        const int k = (int)(ent & 0xFFFFu);
        const float p = f_of_bf16(ent >> 16);
        us4 vv = *reinterpret_cast<const us4*>(Vrow + (size_t)k * 128 + eq * 4);
        a0 += p * f_of_bf16(vv.x);
        a1 += p * f_of_bf16(vv.y);
        a2 += p * f_of_bf16(vv.z);
        a3 += p * f_of_bf16(vv.w);
    }
    const float gsel = sel[b * 8 + h];
    float* orow = out + ((size_t)(b * 1024 + t0 + qrow)) * 128 + eq * 4;
    atomicAdd(&orow[0], gsel * a0);
    atomicAdd(&orow[1], gsel * a1);
    atomicAdd(&orow[2], gsel * a2);
    atomicAdd(&orow[3], gsel * a3);
}

extern "C" void kernel_launch(void* const* d_in, const int* in_sizes, int n_in,
                              void* d_out, int out_size, void* d_ws, size_t ws_size,
                              hipStream_t stream) {
    (void)in_sizes; (void)n_in; (void)ws_size;
    const float* x   = (const float*)d_in[0];
    const int* mask  = (const int*)d_in[1];
    const float* wq  = (const float*)d_in[2];
    const float* wk  = (const float*)d_in[3];
    const float* wv  = (const float*)d_in[4];
    const float* wsl = (const float*)d_in[5];
    const float* bsl = (const float*)d_in[6];
    float* out = (float*)d_out;

    // ws: sel 4KB | mp 1MB | xb 2MB | Wt 768KB | Q 16MB | K 16MB | V 16MB
    char* wsc = (char*)d_ws;
    float*    sel = (float*)wsc;
    u64*      mp  = (u64*)(wsc + 4096);
    ushort_t* xb  = (ushort_t*)(wsc + 4096 + 1048576);
    ushort_t* Wt  = (ushort_t*)(wsc + 4096 + 1048576 + 2097152);
    ushort_t* Qb  = (ushort_t*)(wsc + 4096 + 1048576 + 2097152 + 786432);
    ushort_t* Kb  = Qb + (size_t)8388608;
    ushort_t* Vb  = Kb + (size_t)8388608;

    hipMemsetAsync(d_out, 0, (size_t)out_size * sizeof(float), stream);
    prep_all<<<3120, 256, 0, stream>>>(x, xb, wq, wk, wv, Wt, mask, mp);
    sel_kernel<<<8, 1024, 0, stream>>>(x, wsl, bsl, sel);
    proj_gemm<<<dim3(128, 48), 256, 0, stream>>>(xb, Wt, Qb, Kb, Vb);
    attn_kernel<<<4096, 512, 0, stream>>>(Qb, Kb, Vb, mp, sel, out);
}

// Round 8
// 268.118 us; speedup vs baseline: 1.3092x; 1.3092x over previous
//
#include <hip/hip_runtime.h>
#include <hip/hip_bf16.h>
#include <math.h>

#define SCALE 0.08838834764831845f  // 1/sqrt(128)

using short8  = __attribute__((ext_vector_type(8))) short;
using short4v = __attribute__((ext_vector_type(4))) short;
using us4     = __attribute__((ext_vector_type(4))) unsigned short;
using f32x4   = __attribute__((ext_vector_type(4))) float;
typedef unsigned long long u64;
typedef unsigned short ushort_t;

static __device__ __forceinline__ ushort_t bf16_of(float f) {
    __hip_bfloat16 h = __float2bfloat16(f);
    return *reinterpret_cast<ushort_t*>(&h);
}
static __device__ __forceinline__ float f_of_bf16(unsigned int u) {
    union { unsigned int i; float f; } v; v.i = u << 16; return v.f;
}

// ---------------- fused prep kernel ----------------
// grid 3120 x 256:
//   [0,1024)    : x -> bf16
//   [1024,1072) : W -> bf16 transposed [3072][128]
//   [1072,3120) : mask bit-pack (8192 rows x 16 u64)
__global__ __launch_bounds__(256)
void prep_all(const float* __restrict__ x, ushort_t* __restrict__ xb,
              const float* __restrict__ wq, const float* __restrict__ wk,
              const float* __restrict__ wv, ushort_t* __restrict__ Wt,
              const int* __restrict__ mask, u64* __restrict__ mp) {
    __shared__ float tile[64][129];
    const int bx = blockIdx.x;
    const int tid = threadIdx.x;
    if (bx < 1024) {
        const int i = bx * 256 + tid;
        float4 v = reinterpret_cast<const float4*>(x)[i];
        short4v o;
        o.x = (short)bf16_of(v.x); o.y = (short)bf16_of(v.y);
        o.z = (short)bf16_of(v.z); o.w = (short)bf16_of(v.w);
        reinterpret_cast<short4v*>(xb)[i] = o;
    } else if (bx < 1072) {
        const int wb = bx - 1024;
        const int mat = wb >> 4;
        const int n0 = (wb & 15) * 64;
        const float* W = (mat == 0) ? wq : (mat == 1) ? wk : wv;
        for (int idx = tid; idx < 8192; idx += 256) {
            const int k = idx >> 6, c = idx & 63;
            tile[c][k] = W[(size_t)k * 1024 + n0 + c];
        }
        __syncthreads();
        for (int idx = tid; idx < 8192; idx += 256) {
            const int c = idx >> 7, k = idx & 127;
            Wt[(size_t)(mat * 1024 + n0 + c) * 128 + k] = bf16_of(tile[c][k]);
        }
    } else {
        const int mb = bx - 1072;
        const int row = mb * 4 + (tid >> 6);
        const int l = tid & 63;
        const int* m = mask + (size_t)row * 1024;
        #pragma unroll
        for (int c = 0; c < 16; ++c) {
            u64 bm = __ballot(m[c * 64 + l] != 0);
            if (l == 0) mp[(size_t)row * 16 + c] = bm;
        }
    }
}

// ---------------- MFMA projection GEMM ----------------
// grid (128, 48), block 256 (4 waves). mat = blockIdx.y>>4 (0 Q,1 K,2 V).
// All outputs row-major bf16 [hb][t][128]; Q pre-scaled.
__global__ __launch_bounds__(256)
void proj_gemm(const ushort_t* __restrict__ xb, const ushort_t* __restrict__ Wt,
               ushort_t* __restrict__ Q, ushort_t* __restrict__ K,
               ushort_t* __restrict__ V) {
    const int tid = threadIdx.x;
    const int w = tid >> 6, l = tid & 63;
    const int l15 = l & 15, lq = l >> 4;
    const int m0 = blockIdx.x * 64;
    const int nb = blockIdx.y;
    const int mat = nb >> 4;
    const int n0 = (nb & 15) * 64;
    const int b = m0 >> 10;

    short8 af[4][4];
    #pragma unroll
    for (int at = 0; at < 4; ++at) {
        const ushort_t* ar = xb + (size_t)(m0 + at * 16 + l15) * 128 + lq * 8;
        #pragma unroll
        for (int f = 0; f < 4; ++f)
            af[at][f] = *reinterpret_cast<const short8*>(ar + f * 32);
    }
    const int ng = n0 + w * 16 + l15;
    const ushort_t* br = Wt + (size_t)(mat * 1024 + ng) * 128 + lq * 8;
    short8 bf[4];
    #pragma unroll
    for (int f = 0; f < 4; ++f)
        bf[f] = *reinterpret_cast<const short8*>(br + f * 32);
    f32x4 acc[4];
    #pragma unroll
    for (int at = 0; at < 4; ++at) acc[at] = (f32x4){0.f, 0.f, 0.f, 0.f};
    #pragma unroll
    for (int at = 0; at < 4; ++at)
        #pragma unroll
        for (int f = 0; f < 4; ++f)
            acc[at] = __builtin_amdgcn_mfma_f32_16x16x32_bf16(af[at][f], bf[f], acc[at], 0, 0, 0);

    const int h = ng >> 7, e = ng & 127;
    ushort_t* O = (mat == 0) ? Q : (mat == 1) ? K : V;
    const float scl = (mat == 0) ? SCALE : 1.0f;
    const size_t obase = (size_t)(h * 8 + b) * 131072 + e;
    #pragma unroll
    for (int at = 0; at < 4; ++at)
        #pragma unroll
        for (int r = 0; r < 4; ++r) {
            const int t = (m0 & 1023) + at * 16 + lq * 4 + r;
            O[obase + (size_t)t * 128] = bf16_of(acc[at][r] * scl);
        }
}

// ---------------- gating (sel) kernel ----------------
__global__ __launch_bounds__(1024)
void sel_kernel(const float* __restrict__ x, const float* __restrict__ wsl,
                const float* __restrict__ bsl, float* __restrict__ sel) {
    __shared__ float part[8][128];
    __shared__ float xm[128];
    __shared__ float lg[8];
    const int b = blockIdx.x;
    const int tid = threadIdx.x;
    const int e = tid & 127, tc = tid >> 7;
    float s = 0.f;
    for (int t = 0; t < 128; ++t)
        s += x[((size_t)b * 1024 + tc * 128 + t) * 128 + e];
    part[tc][e] = s;
    __syncthreads();
    if (tid < 128) {
        float tot = 0.f;
        #pragma unroll
        for (int i = 0; i < 8; ++i) tot += part[i][tid];
        xm[tid] = tot * (1.0f / 1024.0f);
    }
    __syncthreads();
    if (tid < 8) {
        float d = 0.f;
        for (int e2 = 0; e2 < 128; ++e2) d += xm[e2] * wsl[tid * 128 + e2];
        lg[tid] = d + bsl[tid];
    }
    __syncthreads();
    if (tid == 0) {
        float mx = lg[0];
        for (int hh = 1; hh < 8; ++hh) mx = fmaxf(mx, lg[hh]);
        float se = 0.f; float ex[8];
        for (int hh = 0; hh < 8; ++hh) { ex[hh] = expf(lg[hh] - mx); se += ex[hh]; }
        for (int hh = 0; hh < 8; ++hh) sel[b * 8 + hh] = ex[hh] / se;
    }
}

// ---------------- MFMA attention: all-heads-per-block, no atomics ----------------
// grid 512 = 8 batches * 64 q-tiles; block 512 (8 waves); head loop inside.
// Bijective XCD swizzle: XCD x owns batch b=x (L2-resident per-head K/Q/V).
__global__ __launch_bounds__(512, 4)
void attn_kernel(const ushort_t* __restrict__ Qb, const ushort_t* __restrict__ Kb,
                 const ushort_t* __restrict__ Vb, const u64* __restrict__ mp,
                 const float* __restrict__ sel, float* __restrict__ out) {
    __shared__ float S[16 * 1024];   // 64 KB; support list aliases it
    __shared__ int cnt[16];
    unsigned int* list = reinterpret_cast<unsigned int*>(S);

    const int tid = threadIdx.x;
    const int w = tid >> 6, l = tid & 63;
    const int l15 = l & 15, lq = l >> 4;
    const int orig = (int)blockIdx.x;
    const int swz = (orig & 7) * 64 + (orig >> 3);   // XCD-chunked remap (512 % 8 == 0)
    const int b = swz >> 6;                          // == orig & 7 : batch locked to XCD
    const int qt = swz & 63;
    const int t0 = qt * 16;
    const int rowbase = b * 1024 + t0;

    const int qrow = 2 * w + (l & 1);   // row for transpose/solve/compact (parity)
    const int lh = l >> 1;
    const int prow = tid >> 5;          // row for PV (same wave's rows)
    const int eq = tid & 31;

    if (tid < 16) cnt[tid] = 0;

    // ---- hoist head-invariant mask words: rows q=lq*4+r, words w*2, w*2+1 ----
    u64 mw0[4], mw1[4];
    #pragma unroll
    for (int r = 0; r < 4; ++r) {
        const u64* mrow = mp + (size_t)(rowbase + lq * 4 + r) * 16 + w * 2;
        mw0[r] = mrow[0];
        mw1[r] = mrow[1];
    }

    f32x4 oac = {0.f, 0.f, 0.f, 0.f};   // gated head-sum accumulator (prow, eq*4..+3)

    for (int h = 0; h < 8; ++h) {
        const size_t base = (size_t)(h * 8 + b) * 131072;
        __syncthreads();   // prev head's list reads done before S overwrite

        // ---- Q A-frags ----
        short8 qa[4];
        {
            const ushort_t* qrp = Qb + base + (size_t)(t0 + l15) * 128 + lq * 8;
            #pragma unroll
            for (int f = 0; f < 4; ++f)
                qa[f] = *reinterpret_cast<const short8*>(qrp + f * 32);
        }

        // ---- QK^T: sc[i][r] = S[q=lq*4+r][k=(w*8+i)*16+l15] ----
        f32x4 sc[8];
        #pragma unroll
        for (int i = 0; i < 8; ++i) {
            const int kt = w * 8 + i;
            const ushort_t* krow = Kb + base + (size_t)(kt * 16 + l15) * 128 + lq * 8;
            f32x4 acc = {0.f, 0.f, 0.f, 0.f};
            #pragma unroll
            for (int f = 0; f < 4; ++f) {
                short8 kb = *reinterpret_cast<const short8*>(krow + f * 32);
                acc = __builtin_amdgcn_mfma_f32_16x16x32_bf16(qa[f], kb, acc, 0, 0, 0);
            }
            sc[i] = acc;
        }

        // ---- mask (hoisted words; bit=1 -> -1e30) ----
        #pragma unroll
        for (int r = 0; r < 4; ++r) {
            #pragma unroll
            for (int i = 0; i < 8; ++i) {
                const u64 mword = (i < 4) ? mw0[r] : mw1[r];
                const int bit = (i & 3) * 16 + l15;
                if ((mword >> bit) & 1ULL) sc[i][r] = -1e30f;
            }
        }

        // ---- S store (f32, chunk-swizzled) ----
        #pragma unroll
        for (int r = 0; r < 4; ++r) {
            const int q = lq * 4 + r;
            #pragma unroll
            for (int i = 0; i < 8; ++i) {
                const int c = (w * 8 + i) * 4 + (l15 >> 2);
                const int cp = c ^ ((c >> 3) & 7) ^ (q & 7);
                S[q * 1024 + cp * 4 + (l15 & 3)] = sc[i][r];
            }
        }
        __syncthreads();

        // ---- transpose read: lane owns 32 vals of row qrow; z[4j+m] = col 4*lh+128*j+m ----
        float z[32];
        #pragma unroll
        for (int j = 0; j < 8; ++j) {
            const int c = lh + 32 * j;
            const int cp = c ^ ((c >> 3) & 7) ^ (qrow & 7);
            float4 v = *reinterpret_cast<const float4*>(&S[qrow * 1024 + cp * 4]);
            z[4 * j + 0] = v.x; z[4 * j + 1] = v.y;
            z[4 * j + 2] = v.z; z[4 * j + 3] = v.w;
        }
        // rows are wave-private from here on (transpose/compact/PV touch only rows 2w,2w+1)

        // ---- row max (tree + 5 same-parity shfl) ----
        float m16[16];
        #pragma unroll
        for (int j = 0; j < 16; ++j) m16[j] = fmaxf(z[j], z[j + 16]);
        #pragma unroll
        for (int j = 0; j < 8; ++j) m16[j] = fmaxf(m16[j], m16[j + 8]);
        #pragma unroll
        for (int j = 0; j < 4; ++j) m16[j] = fmaxf(m16[j], m16[j + 4]);
        float mx = fmaxf(fmaxf(m16[0], m16[1]), fmaxf(m16[2], m16[3]));
        #pragma unroll
        for (int mm = 2; mm < 64; mm <<= 1) mx = fmaxf(mx, __shfl_xor(mx, mm));

        // ---- Michelot sparsemax, warm start from {z > mx-1} (superset of support) ----
        float tau;
        if (mx < -1e29f) {
            tau = 3e38f;               // fully-masked row -> zero output
        } else {
            tau = mx - 1.0f;
            unsigned prev = 0xFFFFFFFFu;
            for (int it = 0; it < 64; ++it) {
                float s2 = 0.f; unsigned c2 = 0u;
                #pragma unroll
                for (int k = 0; k < 32; ++k) {
                    const float zz = z[k];
                    s2 += (zz > tau) ? zz : 0.f;
                    c2 += (zz > tau) ? 1u : 0u;
                }
                #pragma unroll
                for (int mm = 2; mm < 64; mm <<= 1) {
                    s2 += __shfl_xor(s2, mm);
                    c2 += __shfl_xor(c2, mm);
                }
                if (c2 == prev) break;
                tau = (s2 - 1.f) / (float)c2;
                prev = c2;
            }
        }

        // ---- compact support (k, p-bf16) into list rows 2w,2w+1 (wave-private) ----
        #pragma unroll
        for (int jj = 0; jj < 32; ++jj) {
            const float p = z[jj] - tau;
            if (p > 0.f) {
                const int k = 4 * lh + 128 * (jj >> 2) + (jj & 3);
                const int pos = atomicAdd(&cnt[qrow], 1);
                list[qrow * 1024 + pos] = (unsigned int)k | ((unsigned int)bf16_of(p) << 16);
            }
        }
        // same-wave RAW on cnt/list -> no barrier

        // ---- sparse PV: half-wave = row, lane = e-quad; oac += gsel * p * V[k] ----
        const float gsel = sel[b * 8 + h];
        const int n = cnt[prow];
        const ushort_t* Vrow = Vb + base;
        const unsigned int* lrow = list + prow * 1024;
        for (int j = 0; j < n; ++j) {
            const unsigned int ent = lrow[j];
            const int k = (int)(ent & 0xFFFFu);
            const float gp = gsel * f_of_bf16(ent >> 16);
            us4 vv = *reinterpret_cast<const us4*>(Vrow + (size_t)k * 128 + eq * 4);
            oac[0] += gp * f_of_bf16(vv.x);
            oac[1] += gp * f_of_bf16(vv.y);
            oac[2] += gp * f_of_bf16(vv.z);
            oac[3] += gp * f_of_bf16(vv.w);
        }
        if (eq == 0) cnt[prow] = 0;   // reset by owning half-wave (in-order after reads)
    }

    // ---- single plain store (no atomics, every element covered exactly once) ----
    float* orow = out + ((size_t)(b * 1024 + t0 + prow)) * 128 + eq * 4;
    *reinterpret_cast<float4*>(orow) = (float4){oac[0], oac[1], oac[2], oac[3]};
}

extern "C" void kernel_launch(void* const* d_in, const int* in_sizes, int n_in,
                              void* d_out, int out_size, void* d_ws, size_t ws_size,
                              hipStream_t stream) {
    (void)in_sizes; (void)n_in; (void)ws_size; (void)out_size;
    const float* x   = (const float*)d_in[0];
    const int* mask  = (const int*)d_in[1];
    const float* wq  = (const float*)d_in[2];
    const float* wk  = (const float*)d_in[3];
    const float* wv  = (const float*)d_in[4];
    const float* wsl = (const float*)d_in[5];
    const float* bsl = (const float*)d_in[6];
    float* out = (float*)d_out;

    // ws: sel 4KB | mp 1MB | xb 2MB | Wt 768KB | Q 16MB | K 16MB | V 16MB
    char* wsc = (char*)d_ws;
    float*    sel = (float*)wsc;
    u64*      mp  = (u64*)(wsc + 4096);
    ushort_t* xb  = (ushort_t*)(wsc + 4096 + 1048576);
    ushort_t* Wt  = (ushort_t*)(wsc + 4096 + 1048576 + 2097152);
    ushort_t* Qb  = (ushort_t*)(wsc + 4096 + 1048576 + 2097152 + 786432);
    ushort_t* Kb  = Qb + (size_t)8388608;
    ushort_t* Vb  = Kb + (size_t)8388608;

    prep_all<<<3120, 256, 0, stream>>>(x, xb, wq, wk, wv, Wt, mask, mp);
    sel_kernel<<<8, 1024, 0, stream>>>(x, wsl, bsl, sel);
    proj_gemm<<<dim3(128, 48), 256, 0, stream>>>(xb, Wt, Qb, Kb, Vb);
    attn_kernel<<<512, 512, 0, stream>>>(Qb, Kb, Vb, mp, sel, out);
}